// Round 1
// baseline (18825.792 us; speedup 1.0000x reference)
//
#include <hip/hip_runtime.h>
#include <hip/hip_bf16.h>

// ViT forward, fp32 baseline.
// B=32 C=3 IMG=224 P=16 D=768 H=12 L=12 DM=3072 NC=82 DH=64 S=197

#define B_ 32
#define C_ 3
#define IMG_ 224
#define P_ 16
#define D_ 768
#define H_ 12
#define L_ 12
#define DM_ 3072
#define NC_ 82
#define DH_ 64
#define S_ 197
#define NP_ 196
#define PK_ 768   // C*P*P

// ---------------- im2col: x[B,C,224,224] -> patches[B*196, 768] ----------------
__global__ void im2col_k(const float* __restrict__ x, float* __restrict__ patches) {
    int idx = blockIdx.x * 256 + threadIdx.x;
    const int total = B_ * NP_ * PK_;
    if (idx >= total) return;
    int k = idx % PK_;
    int m = idx / PK_;
    int b = m / NP_;
    int p = m % NP_;
    int c = k >> 8;          // k / 256
    int r = (k >> 4) & 15;
    int col = k & 15;
    int ph = p / 14, pw = p % 14;
    patches[idx] = x[((size_t)(b * C_ + c) * IMG_ + ph * P_ + r) * IMG_ + pw * P_ + col];
}

// ---------------- transpose conv_w [768,768] -> [768,768]^T ----------------
__global__ void transpose768_k(const float* __restrict__ in, float* __restrict__ out) {
    __shared__ float t[32][33];
    int bx = blockIdx.x * 32, by = blockIdx.y * 32;
    int tx = threadIdx.x, ty = threadIdx.y;   // block (32,8)
    for (int i = 0; i < 32; i += 8)
        t[ty + i][tx] = in[(size_t)(by + ty + i) * 768 + bx + tx];
    __syncthreads();
    for (int i = 0; i < 32; i += 8)
        out[(size_t)(bx + ty + i) * 768 + by + tx] = t[tx][ty + i];
}

// ---------------- cls row fill: h[b,0,:] = cls + pos[0,:] ----------------
__global__ void cls_fill_k(const float* __restrict__ cls, const float* __restrict__ pos,
                           float* __restrict__ h) {
    int idx = blockIdx.x * 256 + threadIdx.x;
    if (idx >= B_ * D_) return;
    int b = idx / D_, d = idx % D_;
    h[(size_t)b * S_ * D_ + d] = cls[d] + pos[d];
}

// ---------------- LayerNorm (two-pass, block per row) ----------------
__global__ __launch_bounds__(256) void ln_k(const float* __restrict__ h,
                                            const float* __restrict__ w,
                                            const float* __restrict__ bb,
                                            float* __restrict__ out) {
    int row = blockIdx.x;
    int tid = threadIdx.x;
    const float* xr = h + (size_t)row * D_;
    float x0 = xr[tid], x1 = xr[tid + 256], x2 = xr[tid + 512];
    __shared__ float red[256];
    red[tid] = x0 + x1 + x2;
    __syncthreads();
    for (int off = 128; off; off >>= 1) {
        if (tid < off) red[tid] += red[tid + off];
        __syncthreads();
    }
    float mean = red[0] * (1.0f / D_);
    __syncthreads();
    float d0 = x0 - mean, d1 = x1 - mean, d2 = x2 - mean;
    red[tid] = d0 * d0 + d1 * d1 + d2 * d2;
    __syncthreads();
    for (int off = 128; off; off >>= 1) {
        if (tid < off) red[tid] += red[tid + off];
        __syncthreads();
    }
    float rstd = rsqrtf(red[0] * (1.0f / D_) + 1e-5f);
    float* orow = out + (size_t)row * D_;
    orow[tid]       = d0 * rstd * w[tid]       + bb[tid];
    orow[tid + 256] = d1 * rstd * w[tid + 256] + bb[tid + 256];
    orow[tid + 512] = d2 * rstd * w[tid + 512] + bb[tid + 512];
}

// ---------------- generic fp32 GEMM: C = A[M,K] * B[K,N] (+epilogue) ----------
// BQKV=1: B is per-head [H][D][DH] weight (l-slice), N-tile aligned to 64.
// EPI: 0 = bias, 1 = gelu(bias), 2 = bias+residual, 3 = tanh(bias),
//      4 = qkv scatter to [B,H,S,DH], 5 = patch scatter to h with pos add.
template<int BQKV, int EPI>
__global__ __launch_bounds__(256) void gemm_k(const float* __restrict__ A,
                                              const float* __restrict__ Bm,
                                              const float* __restrict__ bias,
                                              float* out, const float* res,
                                              int M, int N, int K, int ldb) {
    __shared__ float As[16][68];
    __shared__ float Bs[16][68];
    int tid = threadIdx.x;
    int m0 = blockIdx.x * 64, n0 = blockIdx.y * 64;

    const float* bptr;
    int bld;
    if (BQKV) { bptr = Bm + (size_t)(n0 >> 6) * D_ * DH_; bld = 64; }
    else      { bptr = Bm + n0;                            bld = ldb; }

    int ar = tid >> 2, ak = (tid & 3) << 2;     // A-load: row, k-offset
    int bk = tid >> 4, bj = (tid & 15) << 2;    // B-load: k-row, col-offset
    int tm4 = (tid >> 4) << 2, tn4 = (tid & 15) << 2;

    float acc[4][4] = {};
    bool aval = (m0 + ar) < M;
    const float* aptr = A + (size_t)(m0 + ar) * K + ak;

    for (int k0 = 0; k0 < K; k0 += 16) {
        float4 av = aval ? *(const float4*)(aptr + k0) : float4{0.f, 0.f, 0.f, 0.f};
        float4 bv = *(const float4*)(bptr + (size_t)(k0 + bk) * bld + bj);
        As[ak + 0][ar] = av.x; As[ak + 1][ar] = av.y;
        As[ak + 2][ar] = av.z; As[ak + 3][ar] = av.w;
        *(float4*)&Bs[bk][bj] = bv;
        __syncthreads();
        #pragma unroll
        for (int kk = 0; kk < 16; kk++) {
            float a[4], b4[4];
            #pragma unroll
            for (int i = 0; i < 4; i++) a[i] = As[kk][tm4 + i];
            #pragma unroll
            for (int j = 0; j < 4; j++) b4[j] = Bs[kk][tn4 + j];
            #pragma unroll
            for (int i = 0; i < 4; i++)
                #pragma unroll
                for (int j = 0; j < 4; j++)
                    acc[i][j] = fmaf(a[i], b4[j], acc[i][j]);
        }
        __syncthreads();
    }

    int colb = n0 + tn4;
    float4 bv4 = *(const float4*)(bias + colb);
    #pragma unroll
    for (int i = 0; i < 4; i++) {
        int row = m0 + tm4 + i;
        if (row >= M) break;
        float v0 = acc[i][0] + bv4.x;
        float v1 = acc[i][1] + bv4.y;
        float v2 = acc[i][2] + bv4.z;
        float v3 = acc[i][3] + bv4.w;
        if (EPI == 1) {   // exact gelu
            v0 = 0.5f * v0 * (1.0f + erff(v0 * 0.70710678118654752f));
            v1 = 0.5f * v1 * (1.0f + erff(v1 * 0.70710678118654752f));
            v2 = 0.5f * v2 * (1.0f + erff(v2 * 0.70710678118654752f));
            v3 = 0.5f * v3 * (1.0f + erff(v3 * 0.70710678118654752f));
        }
        if (EPI == 3) {
            v0 = tanhf(v0); v1 = tanhf(v1); v2 = tanhf(v2); v3 = tanhf(v3);
        }
        if (EPI == 2) {
            const float4 rv = *(const float4*)(res + (size_t)row * N + colb);
            v0 += rv.x; v1 += rv.y; v2 += rv.z; v3 += rv.w;
        }
        float4 st = {v0, v1, v2, v3};
        if (EPI == 4) {
            int b = row / S_, s = row % S_;
            int hh = colb >> 6, e = colb & 63;
            *(float4*)(out + (((size_t)(b * H_ + hh) * S_ + s) << 6) + e) = st;
        } else if (EPI == 5) {
            int b = row / NP_, p = row % NP_;
            const float4 pv = *(const float4*)(res + (size_t)(1 + p) * D_ + colb);
            st.x += pv.x; st.y += pv.y; st.z += pv.z; st.w += pv.w;
            *(float4*)(out + (size_t)(b * S_ + 1 + p) * D_ + colb) = st;
        } else {
            *(float4*)(out + (size_t)row * N + colb) = st;
        }
    }
}

// ---------------- QK^T: scores[bh, s, t] = q[bh,s,:] . k[bh,t,:] * 0.125 -----
__global__ __launch_bounds__(256) void qk_k(const float* __restrict__ q,
                                            const float* __restrict__ k,
                                            float* __restrict__ scores) {
    __shared__ float qs[64][65];
    __shared__ float ks[64][65];
    int bh = blockIdx.z;
    int s0 = blockIdx.x * 64, t0 = blockIdx.y * 64;
    int tid = threadIdx.x;
    size_t base = (size_t)bh * S_ * DH_;
    int lr = tid >> 4, lc4 = (tid & 15) << 2;
    #pragma unroll
    for (int i = 0; i < 4; i++) {
        int row = lr + i * 16;
        float4 qv = (s0 + row < S_) ? *(const float4*)(q + base + (size_t)(s0 + row) * 64 + lc4)
                                    : float4{0.f, 0.f, 0.f, 0.f};
        float4 kv = (t0 + row < S_) ? *(const float4*)(k + base + (size_t)(t0 + row) * 64 + lc4)
                                    : float4{0.f, 0.f, 0.f, 0.f};
        qs[lc4 + 0][row] = qv.x; qs[lc4 + 1][row] = qv.y;
        qs[lc4 + 2][row] = qv.z; qs[lc4 + 3][row] = qv.w;
        ks[lc4 + 0][row] = kv.x; ks[lc4 + 1][row] = kv.y;
        ks[lc4 + 2][row] = kv.z; ks[lc4 + 3][row] = kv.w;
    }
    __syncthreads();
    int tm4 = (tid >> 4) << 2, tn4 = (tid & 15) << 2;
    float acc[4][4] = {};
    #pragma unroll 16
    for (int kk = 0; kk < 64; kk++) {
        float a[4], b4[4];
        #pragma unroll
        for (int i = 0; i < 4; i++) a[i] = qs[kk][tm4 + i];
        #pragma unroll
        for (int j = 0; j < 4; j++) b4[j] = ks[kk][tn4 + j];
        #pragma unroll
        for (int i = 0; i < 4; i++)
            #pragma unroll
            for (int j = 0; j < 4; j++)
                acc[i][j] = fmaf(a[i], b4[j], acc[i][j]);
    }
    #pragma unroll
    for (int i = 0; i < 4; i++) {
        int s = s0 + tm4 + i;
        if (s >= S_) continue;
        #pragma unroll
        for (int j = 0; j < 4; j++) {
            int t = t0 + tn4 + j;
            if (t < S_)
                scores[((size_t)bh * S_ + s) * S_ + t] = acc[i][j] * 0.125f;
        }
    }
}

// ---------------- softmax over last dim (197), one wave per row --------------
__global__ __launch_bounds__(256) void softmax_k(float* __restrict__ scores) {
    int wid = threadIdx.x >> 6, lane = threadIdx.x & 63;
    long long row = (long long)blockIdx.x * 4 + wid;
    if (row >= (long long)B_ * H_ * S_) return;
    float* p = scores + row * S_;
    float v[4];
    #pragma unroll
    for (int i = 0; i < 4; i++) {
        int idx = lane + i * 64;
        v[i] = (idx < S_) ? p[idx] : -INFINITY;
    }
    float m = fmaxf(fmaxf(v[0], v[1]), fmaxf(v[2], v[3]));
    #pragma unroll
    for (int off = 32; off; off >>= 1) m = fmaxf(m, __shfl_xor(m, off));
    float s = 0.f;
    #pragma unroll
    for (int i = 0; i < 4; i++) {
        v[i] = (lane + i * 64 < S_) ? expf(v[i] - m) : 0.f;
        s += v[i];
    }
    #pragma unroll
    for (int off = 32; off; off >>= 1) s += __shfl_xor(s, off);
    float inv = 1.0f / s;
    #pragma unroll
    for (int i = 0; i < 4; i++) {
        int idx = lane + i * 64;
        if (idx < S_) p[idx] = v[i] * inv;
    }
}

// ---------------- PV: ctx[b, s, h*64+e] = sum_t attn[bh,s,t] * v[bh,t,e] -----
__global__ __launch_bounds__(256) void pv_k(const float* __restrict__ attn,
                                            const float* __restrict__ v,
                                            float* __restrict__ ctx) {
    __shared__ float vs[64][65];
    __shared__ float as_[32][65];
    int bh = blockIdx.y;
    int s0 = blockIdx.x * 32;
    int tid = threadIdx.x;
    int tx = tid & 63, ty = tid >> 6;
    int b = bh / H_, hh = bh % H_;
    size_t vbase = (size_t)bh * S_ * DH_;
    size_t abase = (size_t)bh * S_ * S_;
    float acc[8] = {};
    for (int kt = 0; kt < S_; kt += 64) {
        #pragma unroll
        for (int i = 0; i < 16; i++) {
            int row = ty * 16 + i;
            vs[row][tx] = (kt + row < S_) ? v[vbase + (size_t)(kt + row) * 64 + tx] : 0.f;
        }
        #pragma unroll
        for (int ii = 0; ii < 8; ii++) {
            int flat = tid * 8 + ii;
            int sr = flat >> 6, kc = flat & 63;
            as_[sr][kc] = (s0 + sr < S_ && kt + kc < S_)
                            ? attn[abase + (size_t)(s0 + sr) * S_ + kt + kc] : 0.f;
        }
        __syncthreads();
        #pragma unroll 16
        for (int kk = 0; kk < 64; kk++) {
            float vv = vs[kk][tx];
            #pragma unroll
            for (int r = 0; r < 8; r++)
                acc[r] = fmaf(as_[ty + 4 * r][kk], vv, acc[r]);
        }
        __syncthreads();
    }
    #pragma unroll
    for (int r = 0; r < 8; r++) {
        int s = s0 + ty + 4 * r;
        if (s < S_) ctx[(size_t)(b * S_ + s) * D_ + hh * 64 + tx] = acc[r];
    }
}

// ---------------- head helpers ----------------
__global__ void cls_copy_k(const float* __restrict__ h, float* __restrict__ cbuf) {
    int idx = blockIdx.x * 256 + threadIdx.x;
    if (idx >= B_ * D_) return;
    int b = idx / D_, d = idx % D_;
    cbuf[idx] = h[(size_t)b * S_ * D_ + d];
}

__global__ void head_k(const float* __restrict__ t, const float* __restrict__ Wc,
                       const float* __restrict__ bc, float* __restrict__ out) {
    int b = blockIdx.x;
    int j = threadIdx.x;
    if (j >= NC_) return;
    float acc = bc[j];
    const float* tr = t + (size_t)b * D_;
    for (int k2 = 0; k2 < D_; k2++)
        acc = fmaf(tr[k2], Wc[(size_t)k2 * NC_ + j], acc);
    out[b * NC_ + j] = acc;
}

extern "C" void kernel_launch(void* const* d_in, const int* in_sizes, int n_in,
                              void* d_out, int out_size, void* d_ws, size_t ws_size,
                              hipStream_t stream) {
    const float* x         = (const float*)d_in[0];
    const float* conv_w    = (const float*)d_in[1];
    const float* conv_b    = (const float*)d_in[2];
    const float* cls_token = (const float*)d_in[3];
    const float* pos_emb   = (const float*)d_in[4];
    const float* Wq        = (const float*)d_in[5];
    const float* bq        = (const float*)d_in[6];
    const float* Wk        = (const float*)d_in[7];
    const float* bk        = (const float*)d_in[8];
    const float* Wv        = (const float*)d_in[9];
    const float* bv        = (const float*)d_in[10];
    const float* Wo        = (const float*)d_in[11];
    const float* bo        = (const float*)d_in[12];
    const float* ln1w      = (const float*)d_in[13];
    const float* ln1b      = (const float*)d_in[14];
    const float* W1        = (const float*)d_in[15];
    const float* b1        = (const float*)d_in[16];
    const float* W2        = (const float*)d_in[17];
    const float* b2        = (const float*)d_in[18];
    const float* Wh        = (const float*)d_in[19];
    const float* bh_in     = (const float*)d_in[20];
    const float* Wc        = (const float*)d_in[21];
    const float* bc        = (const float*)d_in[22];
    float* out = (float*)d_out;
    float* ws  = (float*)d_ws;

    size_t off = 0;
    auto alloc = [&](size_t n) { size_t o = off; off += (n + 255) & ~(size_t)255; return o; };
    float* convwT = ws + alloc((size_t)768 * 768);
    float* hbuf   = ws + alloc((size_t)B_ * S_ * D_);
    float* ain    = ws + alloc((size_t)B_ * S_ * D_);
    float* qb     = ws + alloc((size_t)B_ * H_ * S_ * DH_);
    float* kb     = ws + alloc((size_t)B_ * H_ * S_ * DH_);
    float* vb     = ws + alloc((size_t)B_ * H_ * S_ * DH_);
    float* ctx    = ws + alloc((size_t)B_ * S_ * D_);      // also reused as patches
    float* big    = ws + alloc((size_t)B_ * S_ * DM_);     // scores / mlp hidden (aliased)
    float* cbuf   = ws + alloc((size_t)B_ * D_);
    float* tbuf   = ws + alloc((size_t)B_ * D_);
    float* patches = ctx;   // patch buffer dead before ctx's first use
    float* scores  = big;   // scores dead before mlp-hidden's first use
    float* mlph    = big;

    dim3 blk(256);

    transpose768_k<<<dim3(24, 24), dim3(32, 8), 0, stream>>>(conv_w, convwT);
    im2col_k<<<(B_ * NP_ * PK_ + 255) / 256, blk, 0, stream>>>(x, patches);
    // patch GEMM: [6272,768] x [768,768] -> scattered into h with pos+bias
    gemm_k<0, 5><<<dim3(6272 / 64, 768 / 64), blk, 0, stream>>>(
        patches, convwT, conv_b, hbuf, pos_emb, 6272, 768, 768, 768);
    cls_fill_k<<<(B_ * D_ + 255) / 256, blk, 0, stream>>>(cls_token, pos_emb, hbuf);

    const int M = B_ * S_;                 // 6304
    const int gM = (M + 63) / 64;          // 99
    for (int l = 0; l < L_; l++) {
        ln_k<<<M, blk, 0, stream>>>(hbuf, ln1w + l * D_, ln1b + l * D_, ain);
        const float* Wql = Wq + (size_t)l * H_ * D_ * DH_;
        const float* Wkl = Wk + (size_t)l * H_ * D_ * DH_;
        const float* Wvl = Wv + (size_t)l * H_ * D_ * DH_;
        gemm_k<1, 4><<<dim3(gM, 12), blk, 0, stream>>>(ain, Wql, bq + l * 768, qb, nullptr, M, 768, 768, 64);
        gemm_k<1, 4><<<dim3(gM, 12), blk, 0, stream>>>(ain, Wkl, bk + l * 768, kb, nullptr, M, 768, 768, 64);
        gemm_k<1, 4><<<dim3(gM, 12), blk, 0, stream>>>(ain, Wvl, bv + l * 768, vb, nullptr, M, 768, 768, 64);
        qk_k<<<dim3(4, 4, B_ * H_), blk, 0, stream>>>(qb, kb, scores);
        softmax_k<<<(B_ * H_ * S_ + 3) / 4, blk, 0, stream>>>(scores);
        pv_k<<<dim3(7, B_ * H_), blk, 0, stream>>>(scores, vb, ctx);
        gemm_k<0, 2><<<dim3(gM, 12), blk, 0, stream>>>(
            ctx, Wo + (size_t)l * D_ * D_, bo + l * D_, hbuf, hbuf, M, 768, 768, 768);
        gemm_k<0, 1><<<dim3(gM, 48), blk, 0, stream>>>(
            hbuf, W1 + (size_t)l * D_ * DM_, b1 + l * DM_, mlph, nullptr, M, 3072, 768, 3072);
        gemm_k<0, 2><<<dim3(gM, 12), blk, 0, stream>>>(
            mlph, W2 + (size_t)l * DM_ * D_, b2 + l * D_, hbuf, hbuf, M, 768, 3072, 768);
    }

    cls_copy_k<<<(B_ * D_ + 255) / 256, blk, 0, stream>>>(hbuf, cbuf);
    gemm_k<0, 3><<<dim3(1, 12), blk, 0, stream>>>(cbuf, Wh, bh_in, tbuf, nullptr, B_, 768, 768, 768);
    head_k<<<dim3(B_), dim3(128), 0, stream>>>(tbuf, Wc, bc, out);
}

// Round 3
// 6175.558 us; speedup vs baseline: 3.0484x; 3.0484x over previous
//
#include <hip/hip_runtime.h>
#include <hip/hip_bf16.h>

// ViT forward: bf16-MFMA GEMMs (fp32 accum), fp32 attention core + LN.
// B=32 C=3 IMG=224 P=16 D=768 H=12 L=12 DM=3072 NC=82 DH=64 S=197

#define B_ 32
#define C_ 3
#define IMG_ 224
#define P_ 16
#define D_ 768
#define H_ 12
#define L_ 12
#define DM_ 3072
#define NC_ 82
#define DH_ 64
#define S_ 197
#define NP_ 196
#define PK_ 768

typedef __attribute__((ext_vector_type(8))) short short8;   // 8 bf16 frag
typedef __attribute__((ext_vector_type(4))) short short4v;  // 4 bf16 pack
typedef __attribute__((ext_vector_type(4))) float f32x4;

__device__ __forceinline__ unsigned short f2bf(float x) {
    union { float f; unsigned u; } v; v.f = x;
    return (unsigned short)((v.u + 0x7fff + ((v.u >> 16) & 1)) >> 16);
}
__device__ __forceinline__ int swz(int r) { return (r ^ (r >> 2)) & 3; }

// ---------------- flat fp32 -> bf16 cast (n % 4 == 0) ----------------
__global__ void cast_bf16_k(const float* __restrict__ in, unsigned short* __restrict__ out, int n) {
    int i = (blockIdx.x * 256 + threadIdx.x) * 4;
    if (i >= n) return;
    float4 v = *(const float4*)(in + i);
    short4v o;
    o.x = (short)f2bf(v.x); o.y = (short)f2bf(v.y);
    o.z = (short)f2bf(v.z); o.w = (short)f2bf(v.w);
    *(short4v*)(out + i) = o;
}

// ---- per-layer weight prep: transpose+cast layer l's QKV/Wo/W1/W2 to bf16 [N][K] ----
// one block = one 32x32 tile. tile ranges: qkv 1728, wo 576, w1 2304, w2 2304 = 6912.
__global__ void prep_layer_k(const float* __restrict__ Wq, const float* __restrict__ Wk,
                             const float* __restrict__ Wv, const float* __restrict__ Wo,
                             const float* __restrict__ W1, const float* __restrict__ W2,
                             unsigned short* __restrict__ qkvt, unsigned short* __restrict__ wot,
                             unsigned short* __restrict__ w1t, unsigned short* __restrict__ w2t,
                             int l) {
    __shared__ float t[32][33];
    int bid = blockIdx.x;
    const float* in; unsigned short* out;
    int R, C, rt, ct;
    if (bid < 1728) {                     // Wq/Wk/Wv: [l][h][768][64] -> rows which*768+h*64+e
        int which = bid / 576, rem = bid % 576;
        int h = rem / 48, tt = rem % 48;
        rt = tt >> 1; ct = tt & 1;
        const float* W = which == 0 ? Wq : which == 1 ? Wk : Wv;
        in = W + ((size_t)l * 12 + h) * (768 * 64);
        out = qkvt + ((size_t)which * 768 + h * 64) * 768;
        R = 768; C = 64;
    } else if (bid < 2304) {              // Wo: [768][768]
        int tt = bid - 1728;
        rt = tt / 24; ct = tt % 24;
        in = Wo + (size_t)l * 768 * 768; out = wot; R = 768; C = 768;
    } else if (bid < 4608) {              // W1: [768][3072]
        int tt = bid - 2304;
        rt = tt / 96; ct = tt % 96;
        in = W1 + (size_t)l * 768 * 3072; out = w1t; R = 768; C = 3072;
    } else {                              // W2: [3072][768]
        int tt = bid - 4608;
        rt = tt / 24; ct = tt % 24;
        in = W2 + (size_t)l * 3072 * 768; out = w2t; R = 3072; C = 768;
    }
    int r0 = rt * 32, c0 = ct * 32;
    int tx = threadIdx.x, ty = threadIdx.y;   // (32,8)
    #pragma unroll
    for (int i = 0; i < 32; i += 8)
        t[ty + i][tx] = in[(size_t)(r0 + ty + i) * C + c0 + tx];
    __syncthreads();
    #pragma unroll
    for (int i = 0; i < 32; i += 8)
        out[(size_t)(c0 + ty + i) * R + r0 + tx] = f2bf(t[tx][ty + i]);
}

// ---------------- im2col: x[B,C,224,224] -> patches[B*196, 768] bf16 ----------------
__global__ void im2col_k(const float* __restrict__ x, unsigned short* __restrict__ patches) {
    int idx = blockIdx.x * 256 + threadIdx.x;
    if (idx >= B_ * NP_ * PK_) return;
    int k = idx % PK_;
    int m = idx / PK_;
    int b = m / NP_;
    int p = m % NP_;
    int c = k >> 8;
    int r = (k >> 4) & 15;
    int col = k & 15;
    int ph = p / 14, pw = p % 14;
    patches[idx] = f2bf(x[((size_t)(b * C_ + c) * IMG_ + ph * P_ + r) * IMG_ + pw * P_ + col]);
}

// ---------------- cls row fill ----------------
__global__ void cls_fill_k(const float* __restrict__ cls, const float* __restrict__ pos,
                           float* __restrict__ h) {
    int idx = blockIdx.x * 256 + threadIdx.x;
    if (idx >= B_ * D_) return;
    int b = idx / D_, d = idx % D_;
    h[(size_t)b * S_ * D_ + d] = cls[d] + pos[d];
}

// ---------------- LayerNorm: fp32 in -> bf16 out ----------------
__global__ __launch_bounds__(256) void ln_k(const float* __restrict__ h,
                                            const float* __restrict__ w,
                                            const float* __restrict__ bb,
                                            unsigned short* __restrict__ out) {
    int row = blockIdx.x;
    int tid = threadIdx.x;
    const float* xr = h + (size_t)row * D_;
    float x0 = xr[tid], x1 = xr[tid + 256], x2 = xr[tid + 512];
    __shared__ float red[256];
    red[tid] = x0 + x1 + x2;
    __syncthreads();
    for (int off = 128; off; off >>= 1) {
        if (tid < off) red[tid] += red[tid + off];
        __syncthreads();
    }
    float mean = red[0] * (1.0f / D_);
    __syncthreads();
    float d0 = x0 - mean, d1 = x1 - mean, d2 = x2 - mean;
    red[tid] = d0 * d0 + d1 * d1 + d2 * d2;
    __syncthreads();
    for (int off = 128; off; off >>= 1) {
        if (tid < off) red[tid] += red[tid + off];
        __syncthreads();
    }
    float rstd = rsqrtf(red[0] * (1.0f / D_) + 1e-5f);
    unsigned short* orow = out + (size_t)row * D_;
    orow[tid]       = f2bf(d0 * rstd * w[tid]       + bb[tid]);
    orow[tid + 256] = f2bf(d1 * rstd * w[tid + 256] + bb[tid + 256]);
    orow[tid + 512] = f2bf(d2 * rstd * w[tid + 512] + bb[tid + 512]);
}

// ---------------- bf16 MFMA GEMM: C = A[M,K]·Bt[N,K]^T (+epilogue) ----------------
// 128x128 tile, BK=32, 4 waves (2x2 of 64x64), global_load_lds staging,
// XOR-swizzled LDS (pre-swizzled global source, swizzled ds_read).
// EPI: 1 = bias+gelu -> bf16 outb; 2 = bias+res -> f32 out (+bf16 outb if set);
//      4 = fused-QKV scatter -> f32 out[3][B,H,S,DH]; 5 = patch scatter + pos.
template<int EPI>
__global__ __launch_bounds__(256) void bgemm_k(
    const unsigned short* __restrict__ A, const unsigned short* __restrict__ Bt,
    const float* __restrict__ bias0, const float* __restrict__ bias1,
    const float* __restrict__ bias2, float* __restrict__ out,
    unsigned short* __restrict__ outb, const float* __restrict__ res,
    int M, int N, int K) {
    __shared__ char lds[16384];   // A-tile [128][32]bf16 @0, B-tile @8192
    int tid = threadIdx.x;
    int lane = tid & 63, wid = tid >> 6;
    int m0 = blockIdx.x * 128, n0 = blockIdx.y * 128;

    // staging addresses (2 chunks of 1KB per wave per operand), pre-swizzled source
    const unsigned short* gA[2];
    const unsigned short* gB[2];
    #pragma unroll
    for (int i = 0; i < 2; i++) {
        int f = wid * 2048 + i * 1024 + lane * 16;
        int row = f >> 6;
        int c = (f >> 4) & 3;
        int cs = c ^ swz(row);
        gA[i] = A + (size_t)(m0 + row) * K + cs * 8;
        gB[i] = Bt + (size_t)(n0 + row) * K + cs * 8;
    }

    f32x4 acc[4][4];
    #pragma unroll
    for (int i = 0; i < 4; i++)
        #pragma unroll
        for (int j = 0; j < 4; j++)
            acc[i][j] = (f32x4){0.f, 0.f, 0.f, 0.f};

    int lr = lane & 15, lk = lane >> 4;
    int wm = wid >> 1, wn = wid & 1;

    for (int k0 = 0; k0 < K; k0 += 32) {
        #pragma unroll
        for (int i = 0; i < 2; i++) {
            __builtin_amdgcn_global_load_lds(
                (const __attribute__((address_space(1))) unsigned int*)(gA[i] + k0),
                (__attribute__((address_space(3))) unsigned int*)(lds + wid * 2048 + i * 1024),
                16, 0, 0);
            __builtin_amdgcn_global_load_lds(
                (const __attribute__((address_space(1))) unsigned int*)(gB[i] + k0),
                (__attribute__((address_space(3))) unsigned int*)(lds + 8192 + wid * 2048 + i * 1024),
                16, 0, 0);
        }
        __syncthreads();
        short8 af[4], bfr[4];
        #pragma unroll
        for (int mi = 0; mi < 4; mi++) {
            int ar = wm * 64 + mi * 16 + lr;
            af[mi] = *(const short8*)(lds + ar * 64 + ((lk ^ swz(ar)) << 4));
            int br = wn * 64 + mi * 16 + lr;
            bfr[mi] = *(const short8*)(lds + 8192 + br * 64 + ((lk ^ swz(br)) << 4));
        }
        #pragma unroll
        for (int mi = 0; mi < 4; mi++)
            #pragma unroll
            for (int ni = 0; ni < 4; ni++)
                acc[mi][ni] = __builtin_amdgcn_mfma_f32_16x16x32_bf16(
                    af[mi], bfr[ni], acc[mi][ni], 0, 0, 0);
        __syncthreads();
    }

    // epilogue: D row = (lane>>4)*4 + r, col = lane&15 within each 16x16 frag
    int lcol = lane & 15, lrg = lane >> 4;
    #pragma unroll
    for (int mi = 0; mi < 4; mi++) {
        #pragma unroll
        for (int r = 0; r < 4; r++) {
            int row = m0 + wm * 64 + mi * 16 + lrg * 4 + r;
            if (row >= M) continue;
            #pragma unroll
            for (int ni = 0; ni < 4; ni++) {
                int col = n0 + wn * 64 + ni * 16 + lcol;
                float v = acc[mi][ni][r];
                if (EPI == 1) {
                    v += bias0[col];
                    v = 0.5f * v * (1.0f + erff(v * 0.70710678118654752f));
                    outb[(size_t)row * N + col] = f2bf(v);
                } else if (EPI == 2) {
                    v += bias0[col] + res[(size_t)row * N + col];
                    out[(size_t)row * N + col] = v;
                    if (outb) outb[(size_t)row * N + col] = f2bf(v);
                } else if (EPI == 4) {
                    int which = (col >= 1536) ? 2 : (col >= 768 ? 1 : 0);
                    int cc = col - which * 768;
                    const float* bp = (which == 0) ? bias0 : (which == 1) ? bias1 : bias2;
                    v += bp[cc];
                    int b = row / S_, s = row % S_;
                    int hh = cc >> 6, e = cc & 63;
                    out[(size_t)which * (B_ * H_ * S_ * DH_) +
                        (((size_t)(b * H_ + hh) * S_ + s) << 6) + e] = v;
                } else if (EPI == 5) {
                    int b = row / NP_, p = row % NP_;
                    v += bias0[col] + res[(size_t)(1 + p) * D_ + col];
                    out[(size_t)(b * S_ + 1 + p) * D_ + col] = v;
                }
            }
        }
    }
}

// ---------------- QK^T (fp32): scores[bh,s,t] ----------------
__global__ __launch_bounds__(256) void qk_k(const float* __restrict__ q,
                                            const float* __restrict__ k,
                                            float* __restrict__ scores) {
    __shared__ float qs[64][65];
    __shared__ float ks[64][65];
    int bh = blockIdx.z;
    int s0 = blockIdx.x * 64, t0 = blockIdx.y * 64;
    int tid = threadIdx.x;
    size_t base = (size_t)bh * S_ * DH_;
    int lr = tid >> 4, lc4 = (tid & 15) << 2;
    #pragma unroll
    for (int i = 0; i < 4; i++) {
        int row = lr + i * 16;
        float4 qv = (s0 + row < S_) ? *(const float4*)(q + base + (size_t)(s0 + row) * 64 + lc4)
                                    : float4{0.f, 0.f, 0.f, 0.f};
        float4 kv = (t0 + row < S_) ? *(const float4*)(k + base + (size_t)(t0 + row) * 64 + lc4)
                                    : float4{0.f, 0.f, 0.f, 0.f};
        qs[lc4 + 0][row] = qv.x; qs[lc4 + 1][row] = qv.y;
        qs[lc4 + 2][row] = qv.z; qs[lc4 + 3][row] = qv.w;
        ks[lc4 + 0][row] = kv.x; ks[lc4 + 1][row] = kv.y;
        ks[lc4 + 2][row] = kv.z; ks[lc4 + 3][row] = kv.w;
    }
    __syncthreads();
    int tm4 = (tid >> 4) << 2, tn4 = (tid & 15) << 2;
    float acc[4][4] = {};
    #pragma unroll 16
    for (int kk = 0; kk < 64; kk++) {
        float a[4], b4[4];
        #pragma unroll
        for (int i = 0; i < 4; i++) a[i] = qs[kk][tm4 + i];
        #pragma unroll
        for (int j = 0; j < 4; j++) b4[j] = ks[kk][tn4 + j];
        #pragma unroll
        for (int i = 0; i < 4; i++)
            #pragma unroll
            for (int j = 0; j < 4; j++)
                acc[i][j] = fmaf(a[i], b4[j], acc[i][j]);
    }
    #pragma unroll
    for (int i = 0; i < 4; i++) {
        int s = s0 + tm4 + i;
        if (s >= S_) continue;
        #pragma unroll
        for (int j = 0; j < 4; j++) {
            int t = t0 + tn4 + j;
            if (t < S_)
                scores[((size_t)bh * S_ + s) * S_ + t] = acc[i][j] * 0.125f;
        }
    }
}

// ---------------- softmax over last dim (197) ----------------
__global__ __launch_bounds__(256) void softmax_k(float* __restrict__ scores) {
    int wid = threadIdx.x >> 6, lane = threadIdx.x & 63;
    long long row = (long long)blockIdx.x * 4 + wid;
    if (row >= (long long)B_ * H_ * S_) return;
    float* p = scores + row * S_;
    float v[4];
    #pragma unroll
    for (int i = 0; i < 4; i++) {
        int idx = lane + i * 64;
        v[i] = (idx < S_) ? p[idx] : -INFINITY;
    }
    float m = fmaxf(fmaxf(v[0], v[1]), fmaxf(v[2], v[3]));
    #pragma unroll
    for (int off = 32; off; off >>= 1) m = fmaxf(m, __shfl_xor(m, off));
    float s = 0.f;
    #pragma unroll
    for (int i = 0; i < 4; i++) {
        v[i] = (lane + i * 64 < S_) ? expf(v[i] - m) : 0.f;
        s += v[i];
    }
    #pragma unroll
    for (int off = 32; off; off >>= 1) s += __shfl_xor(s, off);
    float inv = 1.0f / s;
    #pragma unroll
    for (int i = 0; i < 4; i++) {
        int idx = lane + i * 64;
        if (idx < S_) p[idx] = v[i] * inv;
    }
}

// ---------------- PV (fp32 in, bf16 ctx out) ----------------
__global__ __launch_bounds__(256) void pv_k(const float* __restrict__ attn,
                                            const float* __restrict__ v,
                                            unsigned short* __restrict__ ctx) {
    __shared__ float vs[64][65];
    __shared__ float as_[32][65];
    int bh = blockIdx.y;
    int s0 = blockIdx.x * 32;
    int tid = threadIdx.x;
    int tx = tid & 63, ty = tid >> 6;
    int b = bh / H_, hh = bh % H_;
    size_t vbase = (size_t)bh * S_ * DH_;
    size_t abase = (size_t)bh * S_ * S_;
    float acc[8] = {};
    for (int kt = 0; kt < S_; kt += 64) {
        #pragma unroll
        for (int i = 0; i < 16; i++) {
            int row = ty * 16 + i;
            vs[row][tx] = (kt + row < S_) ? v[vbase + (size_t)(kt + row) * 64 + tx] : 0.f;
        }
        #pragma unroll
        for (int ii = 0; ii < 8; ii++) {
            int flat = tid * 8 + ii;
            int sr = flat >> 6, kc = flat & 63;
            as_[sr][kc] = (s0 + sr < S_ && kt + kc < S_)
                            ? attn[abase + (size_t)(s0 + sr) * S_ + kt + kc] : 0.f;
        }
        __syncthreads();
        #pragma unroll 16
        for (int kk = 0; kk < 64; kk++) {
            float vv = vs[kk][tx];
            #pragma unroll
            for (int r = 0; r < 8; r++)
                acc[r] = fmaf(as_[ty + 4 * r][kk], vv, acc[r]);
        }
        __syncthreads();
    }
    #pragma unroll
    for (int r = 0; r < 8; r++) {
        int s = s0 + ty + 4 * r;
        if (s < S_) ctx[(size_t)(b * S_ + s) * D_ + hh * 64 + tx] = f2bf(acc[r]);
    }
}

// ---------------- fp32 GEMM (head only): C = A·B +bias, tanh ----------------
template<int EPI>
__global__ __launch_bounds__(256) void gemm_k(const float* __restrict__ A,
                                              const float* __restrict__ Bm,
                                              const float* __restrict__ bias,
                                              float* out, int M, int N, int K) {
    __shared__ float As[16][68];
    __shared__ float Bs[16][68];
    int tid = threadIdx.x;
    int m0 = blockIdx.x * 64, n0 = blockIdx.y * 64;
    int ar = tid >> 2, ak = (tid & 3) << 2;
    int bk = tid >> 4, bj = (tid & 15) << 2;
    int tm4 = (tid >> 4) << 2, tn4 = (tid & 15) << 2;
    float acc[4][4] = {};
    bool aval = (m0 + ar) < M;
    const float* aptr = A + (size_t)(m0 + ar) * K + ak;
    for (int k0 = 0; k0 < K; k0 += 16) {
        float4 av = aval ? *(const float4*)(aptr + k0) : float4{0.f, 0.f, 0.f, 0.f};
        float4 bv = *(const float4*)(Bm + (size_t)(k0 + bk) * N + n0 + bj);
        As[ak + 0][ar] = av.x; As[ak + 1][ar] = av.y;
        As[ak + 2][ar] = av.z; As[ak + 3][ar] = av.w;
        *(float4*)&Bs[bk][bj] = bv;
        __syncthreads();
        #pragma unroll
        for (int kk = 0; kk < 16; kk++) {
            float a[4], b4[4];
            #pragma unroll
            for (int i = 0; i < 4; i++) a[i] = As[kk][tm4 + i];
            #pragma unroll
            for (int j = 0; j < 4; j++) b4[j] = Bs[kk][tn4 + j];
            #pragma unroll
            for (int i = 0; i < 4; i++)
                #pragma unroll
                for (int j = 0; j < 4; j++)
                    acc[i][j] = fmaf(a[i], b4[j], acc[i][j]);
        }
        __syncthreads();
    }
    int colb = n0 + tn4;
    float4 bv4 = *(const float4*)(bias + colb);
    #pragma unroll
    for (int i = 0; i < 4; i++) {
        int row = m0 + tm4 + i;
        if (row >= M) break;
        float v0 = acc[i][0] + bv4.x;
        float v1 = acc[i][1] + bv4.y;
        float v2 = acc[i][2] + bv4.z;
        float v3 = acc[i][3] + bv4.w;
        if (EPI == 3) { v0 = tanhf(v0); v1 = tanhf(v1); v2 = tanhf(v2); v3 = tanhf(v3); }
        float4 st = {v0, v1, v2, v3};
        *(float4*)(out + (size_t)row * N + colb) = st;
    }
}

// ---------------- head helpers ----------------
__global__ void cls_copy_k(const float* __restrict__ h, float* __restrict__ cbuf) {
    int idx = blockIdx.x * 256 + threadIdx.x;
    if (idx >= B_ * D_) return;
    int b = idx / D_, d = idx % D_;
    cbuf[idx] = h[(size_t)b * S_ * D_ + d];
}

__global__ void head_k(const float* __restrict__ t, const float* __restrict__ Wc,
                       const float* __restrict__ bc, float* __restrict__ out) {
    int b = blockIdx.x;
    int j = threadIdx.x;
    if (j >= NC_) return;
    float acc = bc[j];
    const float* tr = t + (size_t)b * D_;
    for (int k2 = 0; k2 < D_; k2++)
        acc = fmaf(tr[k2], Wc[(size_t)k2 * NC_ + j], acc);
    out[b * NC_ + j] = acc;
}

extern "C" void kernel_launch(void* const* d_in, const int* in_sizes, int n_in,
                              void* d_out, int out_size, void* d_ws, size_t ws_size,
                              hipStream_t stream) {
    const float* x         = (const float*)d_in[0];
    const float* conv_w    = (const float*)d_in[1];
    const float* conv_b    = (const float*)d_in[2];
    const float* cls_token = (const float*)d_in[3];
    const float* pos_emb   = (const float*)d_in[4];
    const float* Wq        = (const float*)d_in[5];
    const float* bq        = (const float*)d_in[6];
    const float* Wk        = (const float*)d_in[7];
    const float* bk        = (const float*)d_in[8];
    const float* Wv        = (const float*)d_in[9];
    const float* bv        = (const float*)d_in[10];
    const float* Wo        = (const float*)d_in[11];
    const float* bo        = (const float*)d_in[12];
    const float* ln1w      = (const float*)d_in[13];
    const float* ln1b      = (const float*)d_in[14];
    const float* W1        = (const float*)d_in[15];
    const float* b1        = (const float*)d_in[16];
    const float* W2        = (const float*)d_in[17];
    const float* b2        = (const float*)d_in[18];
    const float* Wh        = (const float*)d_in[19];
    const float* bh_in     = (const float*)d_in[20];
    const float* Wc        = (const float*)d_in[21];
    const float* bc        = (const float*)d_in[22];
    float* out = (float*)d_out;
    float* ws  = (float*)d_ws;

    const size_t BHSD = (size_t)B_ * H_ * S_ * DH_;   // 4,841,472
    size_t off = 0;
    auto alloc = [&](size_t nf) { size_t o = off; off += (nf + 255) & ~(size_t)255; return o; };
    // per-layer bf16 weight buffers (transposed to [N][K])
    unsigned short* qkvt  = (unsigned short*)(ws + alloc((size_t)2304 * 768 / 2));
    unsigned short* wot   = (unsigned short*)(ws + alloc((size_t)768 * 768 / 2));
    unsigned short* w1t   = (unsigned short*)(ws + alloc((size_t)768 * 3072 / 2));
    unsigned short* w2t   = (unsigned short*)(ws + alloc((size_t)768 * 3072 / 2));
    unsigned short* convwt= (unsigned short*)(ws + alloc((size_t)768 * 768 / 2));
    float* hbuf   = ws + alloc((size_t)B_ * S_ * D_);
    unsigned short* abuf = (unsigned short*)(ws + alloc((size_t)B_ * S_ * D_ / 2)); // bf16 GEMM input
    float* qkvb   = ws + alloc(3 * BHSD);
    unsigned short* ctx = (unsigned short*)(ws + alloc((size_t)B_ * S_ * D_ / 2));
    float* big    = ws + alloc((size_t)B_ * H_ * S_ * S_);   // scores / mlph / patches
    float* cbuf   = ws + alloc((size_t)B_ * D_);
    float* tbuf   = ws + alloc((size_t)B_ * D_);
    unsigned short* patches = (unsigned short*)big;
    float* scores = big;
    unsigned short* mlph = (unsigned short*)big;

    dim3 blk(256);
    dim3 tblk(32, 8);

    // ---- patch embedding (conv weight needs cast only: [D][CPP] k-major already) ----
    cast_bf16_k<<<576, blk, 0, stream>>>(conv_w, convwt, 768 * 768);
    im2col_k<<<(B_ * NP_ * PK_ + 255) / 256, blk, 0, stream>>>(x, patches);
    bgemm_k<5><<<dim3(49, 6), blk, 0, stream>>>(
        patches, convwt, conv_b, nullptr, nullptr, hbuf, nullptr, pos_emb, 6272, 768, 768);
    cls_fill_k<<<(B_ * D_ + 255) / 256, blk, 0, stream>>>(cls_token, pos_emb, hbuf);

    const int M = B_ * S_;          // 6304
    const int gM = (M + 127) / 128; // 50
    for (int l = 0; l < L_; l++) {
        prep_layer_k<<<6912, tblk, 0, stream>>>(Wq, Wk, Wv, Wo, W1, W2,
                                                qkvt, wot, w1t, w2t, l);
        ln_k<<<M, blk, 0, stream>>>(hbuf, ln1w + l * D_, ln1b + l * D_, abuf);
        bgemm_k<4><<<dim3(gM, 18), blk, 0, stream>>>(
            abuf, qkvt, bq + l * 768, bk + l * 768, bv + l * 768,
            qkvb, nullptr, nullptr, M, 2304, 768);
        qk_k<<<dim3(4, 4, B_ * H_), blk, 0, stream>>>(qkvb, qkvb + BHSD, scores);
        softmax_k<<<(B_ * H_ * S_ + 3) / 4, blk, 0, stream>>>(scores);
        pv_k<<<dim3(7, B_ * H_), blk, 0, stream>>>(scores, qkvb + 2 * BHSD, ctx);
        bgemm_k<2><<<dim3(gM, 6), blk, 0, stream>>>(
            ctx, wot, bo + l * 768, nullptr, nullptr,
            hbuf, abuf, hbuf, M, 768, 768);             // dual-write: f32 resid + bf16 mlp-in
        bgemm_k<1><<<dim3(gM, 24), blk, 0, stream>>>(
            abuf, w1t, b1 + l * 3072, nullptr, nullptr,
            nullptr, mlph, nullptr, M, 3072, 768);
        bgemm_k<2><<<dim3(gM, 6), blk, 0, stream>>>(
            mlph, w2t, b2 + l * 768, nullptr, nullptr,
            hbuf, nullptr, hbuf, M, 768, 3072);
    }

    cls_copy_k<<<(B_ * D_ + 255) / 256, blk, 0, stream>>>(hbuf, cbuf);
    gemm_k<3><<<dim3(1, 12), blk, 0, stream>>>(cbuf, Wh, bh_in, tbuf, B_, 768, 768);
    head_k<<<dim3(B_), dim3(128), 0, stream>>>(tbuf, Wc, bc, out);
}

// Round 4
// 4478.870 us; speedup vs baseline: 4.2032x; 1.3788x over previous
//
#include <hip/hip_runtime.h>
#include <hip/hip_bf16.h>

// ViT forward: bf16-MFMA GEMMs + fused bf16-MFMA attention. fp32 residual spine.
// B=32 C=3 IMG=224 P=16 D=768 H=12 L=12 DM=3072 NC=82 DH=64 S=197

#define B_ 32
#define C_ 3
#define IMG_ 224
#define P_ 16
#define D_ 768
#define H_ 12
#define L_ 12
#define DM_ 3072
#define NC_ 82
#define DH_ 64
#define S_ 197
#define NP_ 196
#define PK_ 768
#define BH_ 384                 // B*H
#define QKSZ_ 4841472           // BH*197*64  (q or k plane, shorts)
#define VTP_ 224                // padded t for V^T / PV k-dim
#define VSZ_ 5505024            // BH*64*224 (v^T plane, shorts)
#define PROW_ 232               // P LDS row stride in shorts (464B)

typedef __attribute__((ext_vector_type(8))) short short8;   // 8 bf16 frag
typedef __attribute__((ext_vector_type(4))) short short4v;  // 4 bf16 pack
typedef __attribute__((ext_vector_type(4))) float f32x4;

__device__ __forceinline__ unsigned short f2bf(float x) {
    union { float f; unsigned u; } v; v.f = x;
    return (unsigned short)((v.u + 0x7fff + ((v.u >> 16) & 1)) >> 16);
}
__device__ __forceinline__ int swz(int r) { return (r ^ (r >> 2)) & 3; }

// ---------------- flat fp32 -> bf16 cast (n % 4 == 0) ----------------
__global__ void cast_bf16_k(const float* __restrict__ in, unsigned short* __restrict__ out, int n) {
    int i = (blockIdx.x * 256 + threadIdx.x) * 4;
    if (i >= n) return;
    float4 v = *(const float4*)(in + i);
    short4v o;
    o.x = (short)f2bf(v.x); o.y = (short)f2bf(v.y);
    o.z = (short)f2bf(v.z); o.w = (short)f2bf(v.w);
    *(short4v*)(out + i) = o;
}

// ---------------- zero-fill v^T plane (pads must be 0 for PV) ----------------
__global__ void zfill_k(unsigned short* __restrict__ p) {
    int i = (blockIdx.x * 256 + threadIdx.x) * 8;   // 2688*256*8 == VSZ_
    short8 z = {0,0,0,0,0,0,0,0};
    *(short8*)(p + i) = z;
}

// ---- per-layer weight prep: transpose+cast layer l's QKV/Wo/W1/W2 to bf16 [N][K] ----
__global__ void prep_layer_k(const float* __restrict__ Wq, const float* __restrict__ Wk,
                             const float* __restrict__ Wv, const float* __restrict__ Wo,
                             const float* __restrict__ W1, const float* __restrict__ W2,
                             unsigned short* __restrict__ qkvt, unsigned short* __restrict__ wot,
                             unsigned short* __restrict__ w1t, unsigned short* __restrict__ w2t,
                             int l) {
    __shared__ float t[32][33];
    int bid = blockIdx.x;
    const float* in; unsigned short* out;
    int R, C, rt, ct;
    if (bid < 1728) {                     // Wq/Wk/Wv: [l][h][768][64]
        int which = bid / 576, rem = bid % 576;
        int h = rem / 48, tt = rem % 48;
        rt = tt >> 1; ct = tt & 1;
        const float* W = which == 0 ? Wq : which == 1 ? Wk : Wv;
        in = W + ((size_t)l * 12 + h) * (768 * 64);
        out = qkvt + ((size_t)which * 768 + h * 64) * 768;
        R = 768; C = 64;
    } else if (bid < 2304) {              // Wo: [768][768]
        int tt = bid - 1728;
        rt = tt / 24; ct = tt % 24;
        in = Wo + (size_t)l * 768 * 768; out = wot; R = 768; C = 768;
    } else if (bid < 4608) {              // W1: [768][3072]
        int tt = bid - 2304;
        rt = tt / 96; ct = tt % 96;
        in = W1 + (size_t)l * 768 * 3072; out = w1t; R = 768; C = 3072;
    } else {                              // W2: [3072][768]
        int tt = bid - 4608;
        rt = tt / 24; ct = tt % 24;
        in = W2 + (size_t)l * 3072 * 768; out = w2t; R = 3072; C = 768;
    }
    int r0 = rt * 32, c0 = ct * 32;
    int tx = threadIdx.x, ty = threadIdx.y;   // (32,8)
    #pragma unroll
    for (int i = 0; i < 32; i += 8)
        t[ty + i][tx] = in[(size_t)(r0 + ty + i) * C + c0 + tx];
    __syncthreads();
    #pragma unroll
    for (int i = 0; i < 32; i += 8)
        out[(size_t)(c0 + ty + i) * R + r0 + tx] = f2bf(t[tx][ty + i]);
}

// ---------------- im2col ----------------
__global__ void im2col_k(const float* __restrict__ x, unsigned short* __restrict__ patches) {
    int idx = blockIdx.x * 256 + threadIdx.x;
    if (idx >= B_ * NP_ * PK_) return;
    int k = idx % PK_;
    int m = idx / PK_;
    int b = m / NP_;
    int p = m % NP_;
    int c = k >> 8;
    int r = (k >> 4) & 15;
    int col = k & 15;
    int ph = p / 14, pw = p % 14;
    patches[idx] = f2bf(x[((size_t)(b * C_ + c) * IMG_ + ph * P_ + r) * IMG_ + pw * P_ + col]);
}

// ---------------- cls row fill ----------------
__global__ void cls_fill_k(const float* __restrict__ cls, const float* __restrict__ pos,
                           float* __restrict__ h) {
    int idx = blockIdx.x * 256 + threadIdx.x;
    if (idx >= B_ * D_) return;
    int b = idx / D_, d = idx % D_;
    h[(size_t)b * S_ * D_ + d] = cls[d] + pos[d];
}

// ---------------- LayerNorm: fp32 in -> bf16 out ----------------
__global__ __launch_bounds__(256) void ln_k(const float* __restrict__ h,
                                            const float* __restrict__ w,
                                            const float* __restrict__ bb,
                                            unsigned short* __restrict__ out) {
    int row = blockIdx.x;
    int tid = threadIdx.x;
    const float* xr = h + (size_t)row * D_;
    float x0 = xr[tid], x1 = xr[tid + 256], x2 = xr[tid + 512];
    __shared__ float red[256];
    red[tid] = x0 + x1 + x2;
    __syncthreads();
    for (int off = 128; off; off >>= 1) {
        if (tid < off) red[tid] += red[tid + off];
        __syncthreads();
    }
    float mean = red[0] * (1.0f / D_);
    __syncthreads();
    float d0 = x0 - mean, d1 = x1 - mean, d2 = x2 - mean;
    red[tid] = d0 * d0 + d1 * d1 + d2 * d2;
    __syncthreads();
    for (int off = 128; off; off >>= 1) {
        if (tid < off) red[tid] += red[tid + off];
        __syncthreads();
    }
    float rstd = rsqrtf(red[0] * (1.0f / D_) + 1e-5f);
    unsigned short* orow = out + (size_t)row * D_;
    orow[tid]       = f2bf(d0 * rstd * w[tid]       + bb[tid]);
    orow[tid + 256] = f2bf(d1 * rstd * w[tid + 256] + bb[tid + 256]);
    orow[tid + 512] = f2bf(d2 * rstd * w[tid + 512] + bb[tid + 512]);
}

// ---------------- bf16 MFMA GEMM: C = A[M,K]·Bt[N,K]^T (+epilogue) ----------------
// EPI: 1 = bias+gelu -> bf16 outb; 2 = bias+res -> f32 out (+bf16 outb if set);
//      4 = fused-QKV -> bf16 q/k planes + v^T plane (outb base); 5 = patch scatter + pos.
template<int EPI>
__global__ __launch_bounds__(256) void bgemm_k(
    const unsigned short* __restrict__ A, const unsigned short* __restrict__ Bt,
    const float* __restrict__ bias0, const float* __restrict__ bias1,
    const float* __restrict__ bias2, float* __restrict__ out,
    unsigned short* __restrict__ outb, const float* __restrict__ res,
    int M, int N, int K) {
    __shared__ char lds[16384];   // A-tile [128][32]bf16 @0, B-tile @8192
    int tid = threadIdx.x;
    int lane = tid & 63, wid = tid >> 6;
    int m0 = blockIdx.x * 128, n0 = blockIdx.y * 128;

    const unsigned short* gA[2];
    const unsigned short* gB[2];
    #pragma unroll
    for (int i = 0; i < 2; i++) {
        int f = wid * 2048 + i * 1024 + lane * 16;
        int row = f >> 6;
        int c = (f >> 4) & 3;
        int cs = c ^ swz(row);
        gA[i] = A + (size_t)(m0 + row) * K + cs * 8;
        gB[i] = Bt + (size_t)(n0 + row) * K + cs * 8;
    }

    f32x4 acc[4][4];
    #pragma unroll
    for (int i = 0; i < 4; i++)
        #pragma unroll
        for (int j = 0; j < 4; j++)
            acc[i][j] = (f32x4){0.f, 0.f, 0.f, 0.f};

    int lr = lane & 15, lk = lane >> 4;
    int wm = wid >> 1, wn = wid & 1;

    for (int k0 = 0; k0 < K; k0 += 32) {
        #pragma unroll
        for (int i = 0; i < 2; i++) {
            __builtin_amdgcn_global_load_lds(
                (const __attribute__((address_space(1))) unsigned int*)(gA[i] + k0),
                (__attribute__((address_space(3))) unsigned int*)(lds + wid * 2048 + i * 1024),
                16, 0, 0);
            __builtin_amdgcn_global_load_lds(
                (const __attribute__((address_space(1))) unsigned int*)(gB[i] + k0),
                (__attribute__((address_space(3))) unsigned int*)(lds + 8192 + wid * 2048 + i * 1024),
                16, 0, 0);
        }
        __syncthreads();
        short8 af[4], bfr[4];
        #pragma unroll
        for (int mi = 0; mi < 4; mi++) {
            int ar = wm * 64 + mi * 16 + lr;
            af[mi] = *(const short8*)(lds + ar * 64 + ((lk ^ swz(ar)) << 4));
            int br = wn * 64 + mi * 16 + lr;
            bfr[mi] = *(const short8*)(lds + 8192 + br * 64 + ((lk ^ swz(br)) << 4));
        }
        #pragma unroll
        for (int mi = 0; mi < 4; mi++)
            #pragma unroll
            for (int ni = 0; ni < 4; ni++)
                acc[mi][ni] = __builtin_amdgcn_mfma_f32_16x16x32_bf16(
                    af[mi], bfr[ni], acc[mi][ni], 0, 0, 0);
        __syncthreads();
    }

    int lcol = lane & 15, lrg = lane >> 4;
    #pragma unroll
    for (int mi = 0; mi < 4; mi++) {
        #pragma unroll
        for (int r = 0; r < 4; r++) {
            int row = m0 + wm * 64 + mi * 16 + lrg * 4 + r;
            if (row >= M) continue;
            #pragma unroll
            for (int ni = 0; ni < 4; ni++) {
                int col = n0 + wn * 64 + ni * 16 + lcol;
                float v = acc[mi][ni][r];
                if (EPI == 1) {
                    v += bias0[col];
                    v = 0.5f * v * (1.0f + erff(v * 0.70710678118654752f));
                    outb[(size_t)row * N + col] = f2bf(v);
                } else if (EPI == 2) {
                    v += bias0[col] + res[(size_t)row * N + col];
                    out[(size_t)row * N + col] = v;
                    if (outb) outb[(size_t)row * N + col] = f2bf(v);
                } else if (EPI == 4) {
                    int which = (col >= 1536) ? 2 : (col >= 768 ? 1 : 0);
                    int cc = col - which * 768;
                    const float* bp = (which == 0) ? bias0 : (which == 1) ? bias1 : bias2;
                    v += bp[cc];
                    int b = row / S_, s = row % S_;
                    int hh = cc >> 6, e = cc & 63;
                    size_t bh = (size_t)(b * H_ + hh);
                    unsigned short bfv = f2bf(v);
                    if (which == 0)
                        outb[bh * (S_ * 64) + (size_t)s * 64 + e] = bfv;
                    else if (which == 1)
                        outb[QKSZ_ + bh * (S_ * 64) + (size_t)s * 64 + e] = bfv;
                    else
                        outb[2 * QKSZ_ + bh * (64 * VTP_) + (size_t)e * VTP_ + s] = bfv;
                } else if (EPI == 5) {
                    int b = row / NP_, p = row % NP_;
                    v += bias0[col] + res[(size_t)(1 + p) * D_ + col];
                    out[(size_t)(b * S_ + 1 + p) * D_ + col] = v;
                }
            }
        }
    }
}

// ---------------- fused attention: QK^T + softmax + PV, all MFMA ----------------
// grid (4 s-tiles, 384 bh), 256 thr. Wave w owns q-rows s0+16w..+15.
__global__ __launch_bounds__(256) void attn_k(const unsigned short* __restrict__ qkv,
                                              unsigned short* __restrict__ ctx) {
    __shared__ unsigned short plds[4][16 * PROW_];
    int bh = blockIdx.y;
    int s0 = blockIdx.x * 64;
    int tid = threadIdx.x, lane = tid & 63, w = tid >> 6;
    int lr = lane & 15, lg = lane >> 4;
    int b = bh / H_, hh = bh % H_;

    const unsigned short* qb = qkv + (size_t)bh * (S_ * 64);
    const unsigned short* kb = qkv + QKSZ_ + (size_t)bh * (S_ * 64);
    const unsigned short* vb = qkv + 2 * QKSZ_ + (size_t)bh * (64 * VTP_);

    // Q fragments (A-operand: lane holds Q[row=lr][k=lg*8..+7])
    int qrow = s0 + w * 16 + lr;
    if (qrow > S_ - 1) qrow = S_ - 1;
    short8 qf0 = *(const short8*)(qb + (size_t)qrow * 64 + lg * 8);
    short8 qf1 = *(const short8*)(qb + (size_t)qrow * 64 + 32 + lg * 8);

    // QK^T: 13 t-frags of 16
    f32x4 sc[13];
    #pragma unroll
    for (int j = 0; j < 13; j++) {
        int t = j * 16 + lr;
        if (t > S_ - 1) t = S_ - 1;
        const unsigned short* kr = kb + (size_t)t * 64 + lg * 8;
        short8 kf0 = *(const short8*)(kr);
        short8 kf1 = *(const short8*)(kr + 32);
        f32x4 a = (f32x4){0.f, 0.f, 0.f, 0.f};
        a = __builtin_amdgcn_mfma_f32_16x16x32_bf16(qf0, kf0, a, 0, 0, 0);
        a = __builtin_amdgcn_mfma_f32_16x16x32_bf16(qf1, kf1, a, 0, 0, 0);
        sc[j] = a;
    }

    // softmax (rows live across the 16-lane group lane&15; 4 rows per lane as regs)
    bool pad12 = (lr >= 5);   // frag 12 covers t=192..207; t>=197 invalid
    float mx[4] = {-INFINITY, -INFINITY, -INFINITY, -INFINITY};
    #pragma unroll
    for (int j = 0; j < 13; j++)
        #pragma unroll
        for (int r = 0; r < 4; r++) {
            float v = sc[j][r] * 0.125f;
            if (j == 12 && pad12) v = -INFINITY;
            sc[j][r] = v;
            mx[r] = fmaxf(mx[r], v);
        }
    #pragma unroll
    for (int r = 0; r < 4; r++) {
        mx[r] = fmaxf(mx[r], __shfl_xor(mx[r], 1));
        mx[r] = fmaxf(mx[r], __shfl_xor(mx[r], 2));
        mx[r] = fmaxf(mx[r], __shfl_xor(mx[r], 4));
        mx[r] = fmaxf(mx[r], __shfl_xor(mx[r], 8));
    }
    float sm[4] = {0.f, 0.f, 0.f, 0.f};
    #pragma unroll
    for (int j = 0; j < 13; j++)
        #pragma unroll
        for (int r = 0; r < 4; r++) {
            float e = __expf(sc[j][r] - mx[r]);
            sc[j][r] = e;
            sm[r] += e;
        }
    #pragma unroll
    for (int r = 0; r < 4; r++) {
        sm[r] += __shfl_xor(sm[r], 1);
        sm[r] += __shfl_xor(sm[r], 2);
        sm[r] += __shfl_xor(sm[r], 4);
        sm[r] += __shfl_xor(sm[r], 8);
        sm[r] = 1.0f / sm[r];
    }

    // write P (bf16) to this wave's LDS strip; C/D row = lg*4+r, col = j*16+lr
    unsigned short* pw = plds[w];
    #pragma unroll
    for (int j = 0; j < 13; j++)
        #pragma unroll
        for (int r = 0; r < 4; r++)
            pw[(lg * 4 + r) * PROW_ + j * 16 + lr] = f2bf(sc[j][r] * sm[r]);
    #pragma unroll
    for (int r = 0; r < 4; r++)   // zero pad cols 208..223
        pw[(lg * 4 + r) * PROW_ + 208 + lr] = 0;
    // intra-wave LDS dependency only: compiler orders via lgkmcnt, no barrier.

    // PV: ctx[s][e] = P[s][t]·V^T[e][t], 4 e-frags × 7 k-steps
    #pragma unroll
    for (int ni = 0; ni < 4; ni++) {
        int e = ni * 16 + lr;
        const unsigned short* vr = vb + (size_t)e * VTP_ + lg * 8;
        f32x4 a = (f32x4){0.f, 0.f, 0.f, 0.f};
        #pragma unroll
        for (int kk = 0; kk < 7; kk++) {
            short8 pf = *(const short8*)(pw + lr * PROW_ + kk * 32 + lg * 8);
            short8 vf = *(const short8*)(vr + kk * 32);
            a = __builtin_amdgcn_mfma_f32_16x16x32_bf16(pf, vf, a, 0, 0, 0);
        }
        #pragma unroll
        for (int r = 0; r < 4; r++) {
            int s = s0 + w * 16 + lg * 4 + r;
            if (s < S_)
                ctx[(size_t)(b * S_ + s) * D_ + hh * 64 + e] = f2bf(a[r]);
        }
    }
}

// ---------------- fp32 GEMM (head only) ----------------
template<int EPI>
__global__ __launch_bounds__(256) void gemm_k(const float* __restrict__ A,
                                              const float* __restrict__ Bm,
                                              const float* __restrict__ bias,
                                              float* out, int M, int N, int K) {
    __shared__ float As[16][68];
    __shared__ float Bs[16][68];
    int tid = threadIdx.x;
    int m0 = blockIdx.x * 64, n0 = blockIdx.y * 64;
    int ar = tid >> 2, ak = (tid & 3) << 2;
    int bk = tid >> 4, bj = (tid & 15) << 2;
    int tm4 = (tid >> 4) << 2, tn4 = (tid & 15) << 2;
    float acc[4][4] = {};
    bool aval = (m0 + ar) < M;
    const float* aptr = A + (size_t)(m0 + ar) * K + ak;
    for (int k0 = 0; k0 < K; k0 += 16) {
        float4 av = aval ? *(const float4*)(aptr + k0) : float4{0.f, 0.f, 0.f, 0.f};
        float4 bv = *(const float4*)(Bm + (size_t)(k0 + bk) * N + n0 + bj);
        As[ak + 0][ar] = av.x; As[ak + 1][ar] = av.y;
        As[ak + 2][ar] = av.z; As[ak + 3][ar] = av.w;
        *(float4*)&Bs[bk][bj] = bv;
        __syncthreads();
        #pragma unroll
        for (int kk = 0; kk < 16; kk++) {
            float a[4], b4[4];
            #pragma unroll
            for (int i = 0; i < 4; i++) a[i] = As[kk][tm4 + i];
            #pragma unroll
            for (int j = 0; j < 4; j++) b4[j] = Bs[kk][tn4 + j];
            #pragma unroll
            for (int i = 0; i < 4; i++)
                #pragma unroll
                for (int j = 0; j < 4; j++)
                    acc[i][j] = fmaf(a[i], b4[j], acc[i][j]);
        }
        __syncthreads();
    }
    int colb = n0 + tn4;
    float4 bv4 = *(const float4*)(bias + colb);
    #pragma unroll
    for (int i = 0; i < 4; i++) {
        int row = m0 + tm4 + i;
        if (row >= M) break;
        float v0 = acc[i][0] + bv4.x;
        float v1 = acc[i][1] + bv4.y;
        float v2 = acc[i][2] + bv4.z;
        float v3 = acc[i][3] + bv4.w;
        if (EPI == 3) { v0 = tanhf(v0); v1 = tanhf(v1); v2 = tanhf(v2); v3 = tanhf(v3); }
        float4 st = {v0, v1, v2, v3};
        *(float4*)(out + (size_t)row * N + colb) = st;
    }
}

// ---------------- head helpers ----------------
__global__ void cls_copy_k(const float* __restrict__ h, float* __restrict__ cbuf) {
    int idx = blockIdx.x * 256 + threadIdx.x;
    if (idx >= B_ * D_) return;
    int b = idx / D_, d = idx % D_;
    cbuf[idx] = h[(size_t)b * S_ * D_ + d];
}

__global__ void head_k(const float* __restrict__ t, const float* __restrict__ Wc,
                       const float* __restrict__ bc, float* __restrict__ out) {
    int b = blockIdx.x;
    int j = threadIdx.x;
    if (j >= NC_) return;
    float acc = bc[j];
    const float* tr = t + (size_t)b * D_;
    for (int k2 = 0; k2 < D_; k2++)
        acc = fmaf(tr[k2], Wc[(size_t)k2 * NC_ + j], acc);
    out[b * NC_ + j] = acc;
}

extern "C" void kernel_launch(void* const* d_in, const int* in_sizes, int n_in,
                              void* d_out, int out_size, void* d_ws, size_t ws_size,
                              hipStream_t stream) {
    const float* x         = (const float*)d_in[0];
    const float* conv_w    = (const float*)d_in[1];
    const float* conv_b    = (const float*)d_in[2];
    const float* cls_token = (const float*)d_in[3];
    const float* pos_emb   = (const float*)d_in[4];
    const float* Wq        = (const float*)d_in[5];
    const float* bq        = (const float*)d_in[6];
    const float* Wk        = (const float*)d_in[7];
    const float* bk        = (const float*)d_in[8];
    const float* Wv        = (const float*)d_in[9];
    const float* bv        = (const float*)d_in[10];
    const float* Wo        = (const float*)d_in[11];
    const float* bo        = (const float*)d_in[12];
    const float* ln1w      = (const float*)d_in[13];
    const float* ln1b      = (const float*)d_in[14];
    const float* W1        = (const float*)d_in[15];
    const float* b1        = (const float*)d_in[16];
    const float* W2        = (const float*)d_in[17];
    const float* b2        = (const float*)d_in[18];
    const float* Wh        = (const float*)d_in[19];
    const float* bh_in     = (const float*)d_in[20];
    const float* Wc        = (const float*)d_in[21];
    const float* bc        = (const float*)d_in[22];
    float* out = (float*)d_out;
    float* ws  = (float*)d_ws;

    size_t off = 0;
    auto alloc = [&](size_t nf) { size_t o = off; off += (nf + 255) & ~(size_t)255; return o; };
    unsigned short* qkvt  = (unsigned short*)(ws + alloc((size_t)2304 * 768 / 2));
    unsigned short* wot   = (unsigned short*)(ws + alloc((size_t)768 * 768 / 2));
    unsigned short* w1t   = (unsigned short*)(ws + alloc((size_t)768 * 3072 / 2));
    unsigned short* w2t   = (unsigned short*)(ws + alloc((size_t)768 * 3072 / 2));
    unsigned short* convwt= (unsigned short*)(ws + alloc((size_t)768 * 768 / 2));
    float* hbuf   = ws + alloc((size_t)B_ * S_ * D_);
    unsigned short* abuf = (unsigned short*)(ws + alloc((size_t)B_ * S_ * D_ / 2));
    unsigned short* qkvb = (unsigned short*)(ws + alloc(((size_t)2 * QKSZ_ + VSZ_) / 2 + 128));
    unsigned short* ctx  = (unsigned short*)(ws + alloc((size_t)B_ * S_ * D_ / 2));
    float* big    = ws + alloc((size_t)B_ * S_ * DM_ / 2 + 256);   // mlph bf16 / patches bf16
    float* cbuf   = ws + alloc((size_t)B_ * D_);
    float* tbuf   = ws + alloc((size_t)B_ * D_);
    unsigned short* patches = (unsigned short*)big;
    unsigned short* mlph = (unsigned short*)big;

    dim3 blk(256);
    dim3 tblk(32, 8);

    // v^T plane zero-fill (pads t in [197,224) must be 0; valid region rewritten per layer)
    zfill_k<<<2688, blk, 0, stream>>>(qkvb + 2 * QKSZ_);

    // ---- patch embedding ----
    cast_bf16_k<<<576, blk, 0, stream>>>(conv_w, convwt, 768 * 768);
    im2col_k<<<(B_ * NP_ * PK_ + 255) / 256, blk, 0, stream>>>(x, patches);
    bgemm_k<5><<<dim3(49, 6), blk, 0, stream>>>(
        patches, convwt, conv_b, nullptr, nullptr, hbuf, nullptr, pos_emb, 6272, 768, 768);
    cls_fill_k<<<(B_ * D_ + 255) / 256, blk, 0, stream>>>(cls_token, pos_emb, hbuf);

    const int M = B_ * S_;          // 6304
    const int gM = (M + 127) / 128; // 50
    for (int l = 0; l < L_; l++) {
        prep_layer_k<<<6912, tblk, 0, stream>>>(Wq, Wk, Wv, Wo, W1, W2,
                                                qkvt, wot, w1t, w2t, l);
        ln_k<<<M, blk, 0, stream>>>(hbuf, ln1w + l * D_, ln1b + l * D_, abuf);
        bgemm_k<4><<<dim3(gM, 18), blk, 0, stream>>>(
            abuf, qkvt, bq + l * 768, bk + l * 768, bv + l * 768,
            nullptr, qkvb, nullptr, M, 2304, 768);
        attn_k<<<dim3(4, BH_), blk, 0, stream>>>(qkvb, ctx);
        bgemm_k<2><<<dim3(gM, 6), blk, 0, stream>>>(
            ctx, wot, bo + l * 768, nullptr, nullptr,
            hbuf, abuf, hbuf, M, 768, 768);             // dual-write: f32 resid + bf16 mlp-in
        bgemm_k<1><<<dim3(gM, 24), blk, 0, stream>>>(
            abuf, w1t, b1 + l * 3072, nullptr, nullptr,
            nullptr, mlph, nullptr, M, 3072, 768);
        bgemm_k<2><<<dim3(gM, 6), blk, 0, stream>>>(
            mlph, w2t, b2 + l * 768, nullptr, nullptr,
            hbuf, nullptr, hbuf, M, 768, 3072);
    }

    cls_copy_k<<<(B_ * D_ + 255) / 256, blk, 0, stream>>>(hbuf, cbuf);
    gemm_k<3><<<dim3(1, 12), blk, 0, stream>>>(cbuf, Wh, bh_in, tbuf, B_, 768, 768);
    head_k<<<dim3(B_), dim3(128), 0, stream>>>(tbuf, Wc, bc, out);
}